// Round 7
// baseline (124.040 us; speedup 1.0000x reference)
//
#include <hip/hip_runtime.h>
#include <hip/hip_bf16.h>
#include <stdint.h>

#define BB 4
#define NN 2048
#define FF 128

typedef __attribute__((ext_vector_type(8))) short bf16x8;
typedef __attribute__((ext_vector_type(4))) float f32x4;

__device__ inline unsigned pk_bf16(float a, float b) {
    union { float f; unsigned u; } x, y;
    x.f = a; y.f = b;
    unsigned xu = x.u + (0x7fffu + ((x.u >> 16) & 1u));
    unsigned yu = y.u + (0x7fffu + ((y.u >> 16) & 1u));
    return (xu >> 16) | (yu & 0xffff0000u);
}

#define XT_P 136
#define WT_P 136

// ---------------- Kernel 1: h = x@W via bf16 MFMA, s = h@a_w + a_b, Ht bf16 ---------
// (unchanged — verified)
__global__ __launch_bounds__(256) void k1_proj(
    const float* __restrict__ x, const float* __restrict__ W,
    const float* __restrict__ a_w, const float* __restrict__ a_b,
    uint16_t* __restrict__ Ht, float* __restrict__ s_out)
{
    __shared__ uint16_t xt[16 * XT_P];
    __shared__ uint16_t Wt[128 * WT_P];
    __shared__ float sredw[4 * 16];

    const int t = threadIdx.x;
    const int w = t >> 6, l = t & 63;
    const int m16 = l & 15, q = l >> 4;
    const int b = blockIdx.x >> 7;
    const int n0 = (blockIdx.x & 127) << 4;

    const int c4 = (t & 31) * 4, kh = (t >> 5) * 16;
    float4 wr0[8], wr1[8];
    #pragma unroll
    for (int kk = 0; kk < 8; ++kk) {
        const int k = kh + 2 * kk;
        wr0[kk] = *(const float4*)(W + (size_t)k * 128 + c4);
        wr1[kk] = *(const float4*)(W + (size_t)(k + 1) * 128 + c4);
    }
    {
        const int row = t >> 4, c0 = (t & 15) * 8;
        const float* xr = x + ((size_t)(b * NN + n0 + row)) * FF + c0;
        const float4 v0 = *(const float4*)xr;
        const float4 v1 = *(const float4*)(xr + 4);
        unsigned* dst = (unsigned*)(xt + row * XT_P + c0);
        dst[0] = pk_bf16(v0.x, v0.y); dst[1] = pk_bf16(v0.z, v0.w);
        dst[2] = pk_bf16(v1.x, v1.y); dst[3] = pk_bf16(v1.z, v1.w);
    }
    #pragma unroll
    for (int kk = 0; kk < 8; ++kk) {
        const int k = kh + 2 * kk;
        *(unsigned*)(Wt + (c4 + 0) * WT_P + k) = pk_bf16(wr0[kk].x, wr1[kk].x);
        *(unsigned*)(Wt + (c4 + 1) * WT_P + k) = pk_bf16(wr0[kk].y, wr1[kk].y);
        *(unsigned*)(Wt + (c4 + 2) * WT_P + k) = pk_bf16(wr0[kk].z, wr1[kk].z);
        *(unsigned*)(Wt + (c4 + 3) * WT_P + k) = pk_bf16(wr0[kk].w, wr1[kk].w);
    }
    const int g0 = (2 * w) * 16 + m16, g1 = (2 * w + 1) * 16 + m16;
    const float aw0 = a_w[g0], aw1 = a_w[g1];
    __syncthreads();

    f32x4 acc0 = {}, acc1 = {};
    bf16x8 af[4];
    #pragma unroll
    for (int dk = 0; dk < 4; ++dk)
        af[dk] = *(const bf16x8*)(xt + m16 * XT_P + dk * 32 + q * 8);
    #pragma unroll
    for (int dk = 0; dk < 4; ++dk) {
        bf16x8 b0 = *(const bf16x8*)(Wt + g0 * WT_P + dk * 32 + q * 8);
        bf16x8 b1 = *(const bf16x8*)(Wt + g1 * WT_P + dk * 32 + q * 8);
        acc0 = __builtin_amdgcn_mfma_f32_16x16x32_bf16(af[dk], b0, acc0, 0, 0, 0);
        acc1 = __builtin_amdgcn_mfma_f32_16x16x32_bf16(af[dk], b1, acc1, 0, 0, 0);
    }

    float sp[4];
    #pragma unroll
    for (int r = 0; r < 4; ++r) sp[r] = acc0[r] * aw0 + acc1[r] * aw1;
    #pragma unroll
    for (int off = 1; off < 16; off <<= 1)
        #pragma unroll
        for (int r = 0; r < 4; ++r) sp[r] += __shfl_xor(sp[r], off, 64);
    if (m16 == 0) {
        #pragma unroll
        for (int r = 0; r < 4; ++r) sredw[w * 16 + q * 4 + r] = sp[r];
    }
    {
        uint2 o0 = { pk_bf16(acc0[0], acc0[1]), pk_bf16(acc0[2], acc0[3]) };
        uint2 o1 = { pk_bf16(acc1[0], acc1[1]), pk_bf16(acc1[2], acc1[3]) };
        *(uint2*)(Ht + ((size_t)(b * 128 + g0)) * NN + n0 + q * 4) = o0;
        *(uint2*)(Ht + ((size_t)(b * 128 + g1)) * NN + n0 + q * 4) = o1;
    }
    __syncthreads();
    if (t < 16)
        s_out[b * NN + n0 + t] = sredw[t] + sredw[16 + t] + sredw[32 + t] + sredw[48 + t] + a_b[0];
}

// ---------------- Kernel 2: register-resident split-K attention ----------------------
// Round-0 verified skeleton + 2-deep A/si prefetch (round-5 verified) with two
// latency fixes:
//  (1) Opw/rsw PARITY DOUBLE-BUFFER -> ONE barrier per round (was 2). Round r's
//      barrier separates round r-1's reads of buffer par^1 from round r+1's
//      writes of par^1, so the second barrier is redundant with 2 buffers.
//  (2) sched_barrier(0) after the prefetch-issue cluster pins the A loads early
//      (round-5's VGPR=88 proved the scheduler sank them to their uses,
//      destroying the 2-round issue-to-use distance).
#define JS 8
#define IRND 8

__global__ __launch_bounds__(256, 2) void k2_attn(
    const float* __restrict__ A, const uint16_t* __restrict__ Ht,
    const float* __restrict__ s, uint16_t* __restrict__ po,
    float* __restrict__ prs)
{
    __shared__ float Opw[2][4][16 * 132];   // 67.5 KB: parity double-buffer
    __shared__ float rsw[2][4][16];

    const int t = threadIdx.x;
    const int w = t >> 6, l = t & 63;
    const int m16 = l & 15, q = l >> 4;

    const int bx = blockIdx.x;
    const int js = bx & 7;
    const int is = (bx >> 3) & 15;
    const int b  = bx >> 7;
    const int j0 = js * 256;
    const int ibase = is * 128;

    const float* sb = s + b * NN;
    const float* Ab = A + (size_t)b * NN * NN;
    const uint16_t* Hb = Ht + (size_t)b * FF * NN;

    const int jc0 = j0 + w * 32 + q * 8;
    const int jc1 = j0 + (w + 4) * 32 + q * 8;

    // loop-invariant sj (16 values per lane)
    float4 sj00 = *(const float4*)(sb + jc0);
    float4 sj01 = *(const float4*)(sb + jc0 + 4);
    float4 sj10 = *(const float4*)(sb + jc1);
    float4 sj11 = *(const float4*)(sb + jc1 + 4);

    // h-fragments in registers: 2 chunks x 8 g-tiles (64 VGPR), held all rounds
    bf16x8 hf0[8], hf1[8];
    #pragma unroll
    for (int gt = 0; gt < 8; ++gt) {
        const uint16_t* hp = Hb + (size_t)(gt * 16 + m16) * NN;
        hf0[gt] = *(const bf16x8*)(hp + jc0);
        hf1[gt] = *(const bf16x8*)(hp + jc1);
    }

    // 2-deep A/si prefetch: rounds 0 and 1 in flight before the loop
    const float* Ar0 = Ab + (size_t)(ibase + m16) * NN;
    const float* Ar1 = Ab + (size_t)(ibase + 16 + m16) * NN;
    float4 p000 = *(const float4*)(Ar0 + jc0);
    float4 p001 = *(const float4*)(Ar0 + jc0 + 4);
    float4 p010 = *(const float4*)(Ar0 + jc1);
    float4 p011 = *(const float4*)(Ar0 + jc1 + 4);
    float4 p100 = *(const float4*)(Ar1 + jc0);
    float4 p101 = *(const float4*)(Ar1 + jc0 + 4);
    float4 p110 = *(const float4*)(Ar1 + jc1);
    float4 p111 = *(const float4*)(Ar1 + jc1 + 4);
    float si0 = sb[ibase + m16];
    float si1 = sb[ibase + 16 + m16];

    const size_t slice = (size_t)(js * BB + b);

    #pragma unroll
    for (int r = 0; r < IRND; ++r) {
        const int i0r = ibase + r * 16;
        const int i2  = ibase + ((r + 2) & (IRND - 1)) * 16;
        const int par = r & 1;

        // prefetch round r+2's A + si (2-round latency cover; wraps harmlessly)
        const float* An = Ab + (size_t)(i2 + m16) * NN;
        float4 n00 = *(const float4*)(An + jc0);
        float4 n01 = *(const float4*)(An + jc0 + 4);
        float4 n10 = *(const float4*)(An + jc1);
        float4 n11 = *(const float4*)(An + jc1 + 4);
        const float si2 = sb[i2 + m16];
        // pin the prefetch issues above the compute phase (no code motion across)
        __builtin_amdgcn_sched_barrier(0);

        const float svv[16] = {sj00.x,sj00.y,sj00.z,sj00.w, sj01.x,sj01.y,sj01.z,sj01.w,
                               sj10.x,sj10.y,sj10.z,sj10.w, sj11.x,sj11.y,sj11.z,sj11.w};
        const float avv[16] = {p000.x,p000.y,p000.z,p000.w, p001.x,p001.y,p001.z,p001.w,
                               p010.x,p010.y,p010.z,p010.w, p011.x,p011.y,p011.z,p011.w};
        float pv[16]; float rs = 0.f;
        #pragma unroll
        for (int j = 0; j < 16; ++j) {
            float e = si0 + svv[j];
            e = fmaxf(e, 0.2f * e);               // LeakyReLU(0.2)
            pv[j] = __expf(e + avv[j]);
            rs += pv[j];
        }
        union { unsigned u[4]; bf16x8 v; } fa0, fa1;
        #pragma unroll
        for (int j = 0; j < 4; ++j) {
            fa0.u[j] = pk_bf16(pv[2 * j], pv[2 * j + 1]);
            fa1.u[j] = pk_bf16(pv[8 + 2 * j], pv[9 + 2 * j]);
        }

        // 16 MFMAs: this wave's P x all 128 g (h-frags in regs; 8 indep chains)
        f32x4 acc[8];
        #pragma unroll
        for (int gt = 0; gt < 8; ++gt) {
            f32x4 z = {0.f, 0.f, 0.f, 0.f};
            z = __builtin_amdgcn_mfma_f32_16x16x32_bf16(fa0.v, hf0[gt], z, 0, 0, 0);
            acc[gt] = __builtin_amdgcn_mfma_f32_16x16x32_bf16(fa1.v, hf1[gt], z, 0, 0, 0);
        }

        // row-sum partials: reduce over q within wave (rows = m16)
        rs += __shfl_xor(rs, 16, 64);
        rs += __shfl_xor(rs, 32, 64);
        if (q == 0) rsw[par][w][m16] = rs;

        // stage this wave's O partial into parity buffer
        #pragma unroll
        for (int gt = 0; gt < 8; ++gt)
            #pragma unroll
            for (int rr = 0; rr < 4; ++rr)
                Opw[par][w][(q * 4 + rr) * 132 + gt * 16 + m16] = acc[gt][rr];
        asm volatile("s_waitcnt lgkmcnt(0)\n\ts_barrier" ::: "memory");  // no vmem drain

        // cross-wave reduce + store (unnormalized partials; k3 divides).
        // No trailing barrier: next round writes parity par^1, whose last
        // readers finished before THIS barrier.
        {
            const int row = t >> 4, k8 = (t & 15) * 8;
            float v[8] = {0.f,0.f,0.f,0.f,0.f,0.f,0.f,0.f};
            #pragma unroll
            for (int sl = 0; sl < 4; ++sl) {
                float4 u0 = *(const float4*)&Opw[par][sl][row * 132 + k8];
                float4 u1 = *(const float4*)&Opw[par][sl][row * 132 + k8 + 4];
                v[0] += u0.x; v[1] += u0.y; v[2] += u0.z; v[3] += u0.w;
                v[4] += u1.x; v[5] += u1.y; v[6] += u1.z; v[7] += u1.w;
            }
            unsigned* op = (unsigned*)(po + ((slice * NN + i0r + row) * FF + k8));
            op[0] = pk_bf16(v[0], v[1]); op[1] = pk_bf16(v[2], v[3]);
            op[2] = pk_bf16(v[4], v[5]); op[3] = pk_bf16(v[6], v[7]);
            if (t < 16)
                prs[slice * NN + i0r + t] = rsw[par][0][t] + rsw[par][1][t]
                                          + rsw[par][2][t] + rsw[par][3][t];
        }

        // rotate the 2-deep pipeline
        p000 = p100; p001 = p101; p010 = p110; p011 = p111; si0 = si1;
        p100 = n00;  p101 = n01;  p110 = n10;  p111 = n11;  si1 = si2;
    }
}

// ---------------- Kernel 3: reduce 8 partials, normalize, bias (vectorized) ---------
// (verified) Thread handles 8 consecutive g: uint4 po loads, float4 stores.
__global__ __launch_bounds__(256) void k3_red(
    const uint16_t* __restrict__ po, const float* __restrict__ prs,
    const float* __restrict__ bias, float* __restrict__ out)
{
    const int gid = blockIdx.x * 256 + threadIdx.x;
    const int g8 = (gid & 15) * 8;
    const int i = (gid >> 4) & (NN - 1);
    const int b = gid >> 15;                       // NN*16 threads per batch

    float v[8] = {0.f,0.f,0.f,0.f,0.f,0.f,0.f,0.f};
    float rsum = 0.f;
    #pragma unroll
    for (int js = 0; js < JS; ++js) {
        const size_t base = (size_t)(js * BB + b) * NN + i;
        const uint4 pv_ = *(const uint4*)(po + base * FF + g8);
        const unsigned uu[4] = {pv_.x, pv_.y, pv_.z, pv_.w};
        #pragma unroll
        for (int k = 0; k < 4; ++k) {
            union { unsigned u; float f; } lo, hi;
            lo.u = uu[k] << 16;
            hi.u = uu[k] & 0xffff0000u;
            v[2 * k]     += lo.f;
            v[2 * k + 1] += hi.f;
        }
        rsum += prs[base];
    }
    const float inv = 1.0f / rsum;
    const float4 b0 = *(const float4*)(bias + g8);
    const float4 b1 = *(const float4*)(bias + g8 + 4);
    float4 o0 = { v[0]*inv + b0.x, v[1]*inv + b0.y, v[2]*inv + b0.z, v[3]*inv + b0.w };
    float4 o1 = { v[4]*inv + b1.x, v[5]*inv + b1.y, v[6]*inv + b1.z, v[7]*inv + b1.w };
    float* op = out + ((size_t)(b * NN + i)) * FF + g8;
    *(float4*)op = o0;
    *(float4*)(op + 4) = o1;
}

extern "C" void kernel_launch(void* const* d_in, const int* in_sizes, int n_in,
                              void* d_out, int out_size, void* d_ws, size_t ws_size,
                              hipStream_t stream) {
    const float* x    = (const float*)d_in[0];
    const float* A    = (const float*)d_in[1];
    const float* W    = (const float*)d_in[2];
    const float* a_w  = (const float*)d_in[3];
    const float* a_b  = (const float*)d_in[4];
    const float* bias = (const float*)d_in[5];
    float* out = (float*)d_out;

    char* ws = (char*)d_ws;
    uint16_t* Ht = (uint16_t*)ws;                                  // 2 MB
    float* s = (float*)(ws + 2 * 1024 * 1024);                     // 32 KB (pad to 64K)
    uint16_t* po = (uint16_t*)(ws + 2 * 1024 * 1024 + 65536);      // 16 MB
    float* prs = (float*)(ws + 2 * 1024 * 1024 + 65536 + (size_t)JS * BB * NN * FF * 2);  // 256 KB

    k1_proj<<<BB * (NN / 16), 256, 0, stream>>>(x, W, a_w, a_b, Ht, s);
    k2_attn<<<JS * 16 * BB, 256, 0, stream>>>(A, Ht, s, po, prs);
    k3_red<<<(BB * NN * FF) / (256 * 8), 256, 0, stream>>>(po, prs, bias, out);
}

// Round 8
// 123.953 us; speedup vs baseline: 1.0007x; 1.0007x over previous
//
#include <hip/hip_runtime.h>
#include <hip/hip_bf16.h>
#include <stdint.h>

#define BB 4
#define NN 2048
#define FF 128

typedef __attribute__((ext_vector_type(8))) short bf16x8;
typedef __attribute__((ext_vector_type(4))) float f32x4;

__device__ inline unsigned pk_bf16(float a, float b) {
    union { float f; unsigned u; } x, y;
    x.f = a; y.f = b;
    unsigned xu = x.u + (0x7fffu + ((x.u >> 16) & 1u));
    unsigned yu = y.u + (0x7fffu + ((y.u >> 16) & 1u));
    return (xu >> 16) | (yu & 0xffff0000u);
}

// async global->LDS, 16B per lane. LDS dest is wave-uniform base + lane*16.
__device__ inline void gload_lds16(const float* g, float* l) {
    __builtin_amdgcn_global_load_lds(
        (const __attribute__((address_space(1))) unsigned*)(g),
        (__attribute__((address_space(3))) unsigned*)(l),
        16, 0, 0);
}

#define XT_P 136
#define WT_P 136

// ---------------- Kernel 1: h = x@W via bf16 MFMA, s = h@a_w + a_b, Ht bf16 ---------
// (unchanged — verified)
__global__ __launch_bounds__(256) void k1_proj(
    const float* __restrict__ x, const float* __restrict__ W,
    const float* __restrict__ a_w, const float* __restrict__ a_b,
    uint16_t* __restrict__ Ht, float* __restrict__ s_out)
{
    __shared__ uint16_t xt[16 * XT_P];
    __shared__ uint16_t Wt[128 * WT_P];
    __shared__ float sredw[4 * 16];

    const int t = threadIdx.x;
    const int w = t >> 6, l = t & 63;
    const int m16 = l & 15, q = l >> 4;
    const int b = blockIdx.x >> 7;
    const int n0 = (blockIdx.x & 127) << 4;

    const int c4 = (t & 31) * 4, kh = (t >> 5) * 16;
    float4 wr0[8], wr1[8];
    #pragma unroll
    for (int kk = 0; kk < 8; ++kk) {
        const int k = kh + 2 * kk;
        wr0[kk] = *(const float4*)(W + (size_t)k * 128 + c4);
        wr1[kk] = *(const float4*)(W + (size_t)(k + 1) * 128 + c4);
    }
    {
        const int row = t >> 4, c0 = (t & 15) * 8;
        const float* xr = x + ((size_t)(b * NN + n0 + row)) * FF + c0;
        const float4 v0 = *(const float4*)xr;
        const float4 v1 = *(const float4*)(xr + 4);
        unsigned* dst = (unsigned*)(xt + row * XT_P + c0);
        dst[0] = pk_bf16(v0.x, v0.y); dst[1] = pk_bf16(v0.z, v0.w);
        dst[2] = pk_bf16(v1.x, v1.y); dst[3] = pk_bf16(v1.z, v1.w);
    }
    #pragma unroll
    for (int kk = 0; kk < 8; ++kk) {
        const int k = kh + 2 * kk;
        *(unsigned*)(Wt + (c4 + 0) * WT_P + k) = pk_bf16(wr0[kk].x, wr1[kk].x);
        *(unsigned*)(Wt + (c4 + 1) * WT_P + k) = pk_bf16(wr0[kk].y, wr1[kk].y);
        *(unsigned*)(Wt + (c4 + 2) * WT_P + k) = pk_bf16(wr0[kk].z, wr1[kk].z);
        *(unsigned*)(Wt + (c4 + 3) * WT_P + k) = pk_bf16(wr0[kk].w, wr1[kk].w);
    }
    const int g0 = (2 * w) * 16 + m16, g1 = (2 * w + 1) * 16 + m16;
    const float aw0 = a_w[g0], aw1 = a_w[g1];
    __syncthreads();

    f32x4 acc0 = {}, acc1 = {};
    bf16x8 af[4];
    #pragma unroll
    for (int dk = 0; dk < 4; ++dk)
        af[dk] = *(const bf16x8*)(xt + m16 * XT_P + dk * 32 + q * 8);
    #pragma unroll
    for (int dk = 0; dk < 4; ++dk) {
        bf16x8 b0 = *(const bf16x8*)(Wt + g0 * WT_P + dk * 32 + q * 8);
        bf16x8 b1 = *(const bf16x8*)(Wt + g1 * WT_P + dk * 32 + q * 8);
        acc0 = __builtin_amdgcn_mfma_f32_16x16x32_bf16(af[dk], b0, acc0, 0, 0, 0);
        acc1 = __builtin_amdgcn_mfma_f32_16x16x32_bf16(af[dk], b1, acc1, 0, 0, 0);
    }

    float sp[4];
    #pragma unroll
    for (int r = 0; r < 4; ++r) sp[r] = acc0[r] * aw0 + acc1[r] * aw1;
    #pragma unroll
    for (int off = 1; off < 16; off <<= 1)
        #pragma unroll
        for (int r = 0; r < 4; ++r) sp[r] += __shfl_xor(sp[r], off, 64);
    if (m16 == 0) {
        #pragma unroll
        for (int r = 0; r < 4; ++r) sredw[w * 16 + q * 4 + r] = sp[r];
    }
    {
        uint2 o0 = { pk_bf16(acc0[0], acc0[1]), pk_bf16(acc0[2], acc0[3]) };
        uint2 o1 = { pk_bf16(acc1[0], acc1[1]), pk_bf16(acc1[2], acc1[3]) };
        *(uint2*)(Ht + ((size_t)(b * 128 + g0)) * NN + n0 + q * 4) = o0;
        *(uint2*)(Ht + ((size_t)(b * 128 + g1)) * NN + n0 + q * 4) = o1;
    }
    __syncthreads();
    if (t < 16)
        s_out[b * NN + n0 + t] = sredw[t] + sredw[16 + t] + sredw[32 + t] + sredw[48 + t] + a_b[0];
}

// ---------------- Kernel 2: split-K attention, A staged via global_load_lds ---------
// Round-0 verified skeleton (h-frags in 64 VGPR, Opw single-buffer 2-barrier)
// with A staged through LDS by global_load_lds (double-buffered 2x16KB):
//  - stage for round r+1 issued at TOP of round r (no dependent registers ->
//    compiler cannot sink it; the load IS the prefetch);
//  - vmcnt(0) drain sits a full compute phase after issue, BEFORE po stores
//    (stores are never waited on);
//  - [16][256] f32 tile XOR-swizzled on 16B chunks (chunk c of row rw lives at
//    slot c^(rw&7)): gload_lds writes linearly, so the SOURCE address carries
//    the inverse swizzle; ds_read applies the same XOR -> 2-way conflict (free).
// XCD pinning: b = bx&3 -> each XCD's Ht slice (2 MB) is L2-resident.
#define JS 8
#define IRND 8

__global__ __launch_bounds__(256, 2) void k2_attn(
    const float* __restrict__ A, const uint16_t* __restrict__ Ht,
    const float* __restrict__ s, uint16_t* __restrict__ po,
    float* __restrict__ prs)
{
    __shared__ float Abuf[2][16 * 256];   // 32 KB: A tile double-buffer
    __shared__ float Opw[4][16 * 132];    // 33.8 KB
    __shared__ float rsw[4][16];

    const int t = threadIdx.x;
    const int w = t >> 6, l = t & 63;
    const int m16 = l & 15, q = l >> 4;

    const int bx = blockIdx.x;
    const int b  = bx & 3;                // XCD-pinned batch
    const int js = (bx >> 2) & 7;
    const int is = bx >> 5;
    const int j0 = js * 256;
    const int ibase = is * 128;

    const float* sb = s + b * NN;
    const float* Ab = A + (size_t)b * NN * NN;
    const uint16_t* Hb = Ht + (size_t)b * FF * NN;

    const int jc0 = j0 + w * 32 + q * 8;
    const int jc1 = j0 + (w + 4) * 32 + q * 8;

    // loop-invariant sj (16 values per lane)
    float4 sj00 = *(const float4*)(sb + jc0);
    float4 sj01 = *(const float4*)(sb + jc0 + 4);
    float4 sj10 = *(const float4*)(sb + jc1);
    float4 sj11 = *(const float4*)(sb + jc1 + 4);

    // h-fragments in registers: 2 chunks x 8 g-tiles (64 VGPR), held all rounds
    bf16x8 hf0[8], hf1[8];
    #pragma unroll
    for (int gt = 0; gt < 8; ++gt) {
        const uint16_t* hp = Hb + (size_t)(gt * 16 + m16) * NN;
        hf0[gt] = *(const bf16x8*)(hp + jc0);
        hf1[gt] = *(const bf16x8*)(hp + jc1);
    }

    // all 8 rounds' si up front (8 VGPR, static indexing)
    float si_all[IRND];
    #pragma unroll
    for (int rr = 0; rr < IRND; ++rr) si_all[rr] = sb[ibase + rr * 16 + m16];

    // stage round 0 into Abuf[0]: wave w stages rows 4w..4w+3; lane l supplies
    // swizzled slot l, which holds global chunk l^(row&7).
    #pragma unroll
    for (int k = 0; k < 4; ++k) {
        const int row = (w << 2) + k;
        const float* gp = Ab + (size_t)(ibase + row) * NN + j0 + ((l ^ (row & 7)) << 2);
        gload_lds16(gp, &Abuf[0][row * 256]);
    }
    asm volatile("s_waitcnt vmcnt(0)" ::: "memory");
    __syncthreads();

    const size_t slice = (size_t)(js * BB + b);
    const int s8x = m16 & 7;
    const int bc = (w << 3) + (q << 1);   // lane's base 16B-chunk in the window

    #pragma unroll
    for (int r = 0; r < IRND; ++r) {
        const int i0r = ibase + r * 16;
        const int cur = r & 1;

        // issue next round's stage (no dependent regs -> cannot be sunk)
        if (r < IRND - 1) {
            #pragma unroll
            for (int k = 0; k < 4; ++k) {
                const int row = (w << 2) + k;
                const float* gp = Ab + (size_t)(i0r + 16 + row) * NN + j0
                                + ((l ^ (row & 7)) << 2);
                gload_lds16(gp, &Abuf[cur ^ 1][row * 256]);
            }
        }

        // A-frags from LDS (swizzled read, 2-way max bank aliasing)
        const float* Al = Abuf[cur] + m16 * 256;
        const float4 a00 = *(const float4*)(Al + (((bc)      ^ s8x) << 2));
        const float4 a01 = *(const float4*)(Al + (((bc + 1)  ^ s8x) << 2));
        const float4 a10 = *(const float4*)(Al + (((bc + 32) ^ s8x) << 2));
        const float4 a11 = *(const float4*)(Al + (((bc + 33) ^ s8x) << 2));

        const float svv[16] = {sj00.x,sj00.y,sj00.z,sj00.w, sj01.x,sj01.y,sj01.z,sj01.w,
                               sj10.x,sj10.y,sj10.z,sj10.w, sj11.x,sj11.y,sj11.z,sj11.w};
        const float avv[16] = {a00.x,a00.y,a00.z,a00.w, a01.x,a01.y,a01.z,a01.w,
                               a10.x,a10.y,a10.z,a10.w, a11.x,a11.y,a11.z,a11.w};
        const float si0 = si_all[r];
        float pv[16]; float rs = 0.f;
        #pragma unroll
        for (int j = 0; j < 16; ++j) {
            float e = si0 + svv[j];
            e = fmaxf(e, 0.2f * e);               // LeakyReLU(0.2)
            pv[j] = __expf(e + avv[j]);
            rs += pv[j];
        }
        union { unsigned u[4]; bf16x8 v; } fa0, fa1;
        #pragma unroll
        for (int j = 0; j < 4; ++j) {
            fa0.u[j] = pk_bf16(pv[2 * j], pv[2 * j + 1]);
            fa1.u[j] = pk_bf16(pv[8 + 2 * j], pv[9 + 2 * j]);
        }

        // 16 MFMAs: this wave's P x all 128 g (h-frags in regs; 8 indep chains)
        f32x4 acc[8];
        #pragma unroll
        for (int gt = 0; gt < 8; ++gt) {
            f32x4 z = {0.f, 0.f, 0.f, 0.f};
            z = __builtin_amdgcn_mfma_f32_16x16x32_bf16(fa0.v, hf0[gt], z, 0, 0, 0);
            acc[gt] = __builtin_amdgcn_mfma_f32_16x16x32_bf16(fa1.v, hf1[gt], z, 0, 0, 0);
        }

        // row-sum partials: reduce over q within wave (rows = m16)
        rs += __shfl_xor(rs, 16, 64);
        rs += __shfl_xor(rs, 32, 64);
        if (q == 0) rsw[w][m16] = rs;

        // stage this wave's O partial (stride 132 -> 2-way-max bank aliasing)
        #pragma unroll
        for (int gt = 0; gt < 8; ++gt)
            #pragma unroll
            for (int rr = 0; rr < 4; ++rr)
                Opw[w][(q * 4 + rr) * 132 + gt * 16 + m16] = acc[gt][rr];
        asm volatile("s_waitcnt lgkmcnt(0)\n\ts_barrier" ::: "memory");  // barrier A

        // cross-wave reduce; drain stage loads BEFORE issuing po stores
        {
            const int row = t >> 4, k8 = (t & 15) * 8;
            float v[8] = {0.f,0.f,0.f,0.f,0.f,0.f,0.f,0.f};
            #pragma unroll
            for (int sl = 0; sl < 4; ++sl) {
                float4 u0 = *(const float4*)&Opw[sl][row * 132 + k8];
                float4 u1 = *(const float4*)&Opw[sl][row * 132 + k8 + 4];
                v[0] += u0.x; v[1] += u0.y; v[2] += u0.z; v[3] += u0.w;
                v[4] += u1.x; v[5] += u1.y; v[6] += u1.z; v[7] += u1.w;
            }
            asm volatile("s_waitcnt vmcnt(0)" ::: "memory");  // next A-tile landed
            unsigned* op = (unsigned*)(po + ((slice * NN + i0r + row) * FF + k8));
            op[0] = pk_bf16(v[0], v[1]); op[1] = pk_bf16(v[2], v[3]);
            op[2] = pk_bf16(v[4], v[5]); op[3] = pk_bf16(v[6], v[7]);
            if (t < 16)
                prs[slice * NN + i0r + t] = rsw[0][t] + rsw[1][t] + rsw[2][t] + rsw[3][t];
        }
        asm volatile("s_waitcnt lgkmcnt(0)\n\ts_barrier" ::: "memory");  // barrier B
    }
}

// ---------------- Kernel 3: reduce 8 partials, normalize, bias (vectorized) ---------
// (verified) Thread handles 8 consecutive g: uint4 po loads, float4 stores.
__global__ __launch_bounds__(256) void k3_red(
    const uint16_t* __restrict__ po, const float* __restrict__ prs,
    const float* __restrict__ bias, float* __restrict__ out)
{
    const int gid = blockIdx.x * 256 + threadIdx.x;
    const int g8 = (gid & 15) * 8;
    const int i = (gid >> 4) & (NN - 1);
    const int b = gid >> 15;                       // NN*16 threads per batch

    float v[8] = {0.f,0.f,0.f,0.f,0.f,0.f,0.f,0.f};
    float rsum = 0.f;
    #pragma unroll
    for (int js = 0; js < JS; ++js) {
        const size_t base = (size_t)(js * BB + b) * NN + i;
        const uint4 pv_ = *(const uint4*)(po + base * FF + g8);
        const unsigned uu[4] = {pv_.x, pv_.y, pv_.z, pv_.w};
        #pragma unroll
        for (int k = 0; k < 4; ++k) {
            union { unsigned u; float f; } lo, hi;
            lo.u = uu[k] << 16;
            hi.u = uu[k] & 0xffff0000u;
            v[2 * k]     += lo.f;
            v[2 * k + 1] += hi.f;
        }
        rsum += prs[base];
    }
    const float inv = 1.0f / rsum;
    const float4 b0 = *(const float4*)(bias + g8);
    const float4 b1 = *(const float4*)(bias + g8 + 4);
    float4 o0 = { v[0]*inv + b0.x, v[1]*inv + b0.y, v[2]*inv + b0.z, v[3]*inv + b0.w };
    float4 o1 = { v[4]*inv + b1.x, v[5]*inv + b1.y, v[6]*inv + b1.z, v[7]*inv + b1.w };
    float* op = out + ((size_t)(b * NN + i)) * FF + g8;
    *(float4*)op = o0;
    *(float4*)(op + 4) = o1;
}

extern "C" void kernel_launch(void* const* d_in, const int* in_sizes, int n_in,
                              void* d_out, int out_size, void* d_ws, size_t ws_size,
                              hipStream_t stream) {
    const float* x    = (const float*)d_in[0];
    const float* A    = (const float*)d_in[1];
    const float* W    = (const float*)d_in[2];
    const float* a_w  = (const float*)d_in[3];
    const float* a_b  = (const float*)d_in[4];
    const float* bias = (const float*)d_in[5];
    float* out = (float*)d_out;

    char* ws = (char*)d_ws;
    uint16_t* Ht = (uint16_t*)ws;                                  // 2 MB
    float* s = (float*)(ws + 2 * 1024 * 1024);                     // 32 KB (pad to 64K)
    uint16_t* po = (uint16_t*)(ws + 2 * 1024 * 1024 + 65536);      // 16 MB
    float* prs = (float*)(ws + 2 * 1024 * 1024 + 65536 + (size_t)JS * BB * NN * FF * 2);  // 256 KB

    k1_proj<<<BB * (NN / 16), 256, 0, stream>>>(x, W, a_w, a_b, Ht, s);
    k2_attn<<<JS * 16 * BB, 256, 0, stream>>>(A, Ht, s, po, prs);
    k3_red<<<(BB * NN * FF) / (256 * 8), 256, 0, stream>>>(po, prs, bias, out);
}

// Round 9
// 119.971 us; speedup vs baseline: 1.0339x; 1.0332x over previous
//
#include <hip/hip_runtime.h>
#include <hip/hip_bf16.h>
#include <stdint.h>

#define BB 4
#define NN 2048
#define FF 128

typedef __attribute__((ext_vector_type(8))) short bf16x8;
typedef __attribute__((ext_vector_type(4))) float f32x4;

__device__ inline unsigned pk_bf16(float a, float b) {
    union { float f; unsigned u; } x, y;
    x.f = a; y.f = b;
    unsigned xu = x.u + (0x7fffu + ((x.u >> 16) & 1u));
    unsigned yu = y.u + (0x7fffu + ((y.u >> 16) & 1u));
    return (xu >> 16) | (yu & 0xffff0000u);
}

#define XT_P 136
#define WT_P 136

// ---------------- Kernel 1: h = x@W via bf16 MFMA, s = h@a_w + a_b, Ht bf16 ---------
// (unchanged — verified)
__global__ __launch_bounds__(256) void k1_proj(
    const float* __restrict__ x, const float* __restrict__ W,
    const float* __restrict__ a_w, const float* __restrict__ a_b,
    uint16_t* __restrict__ Ht, float* __restrict__ s_out)
{
    __shared__ uint16_t xt[16 * XT_P];
    __shared__ uint16_t Wt[128 * WT_P];
    __shared__ float sredw[4 * 16];

    const int t = threadIdx.x;
    const int w = t >> 6, l = t & 63;
    const int m16 = l & 15, q = l >> 4;
    const int b = blockIdx.x >> 7;
    const int n0 = (blockIdx.x & 127) << 4;

    const int c4 = (t & 31) * 4, kh = (t >> 5) * 16;
    float4 wr0[8], wr1[8];
    #pragma unroll
    for (int kk = 0; kk < 8; ++kk) {
        const int k = kh + 2 * kk;
        wr0[kk] = *(const float4*)(W + (size_t)k * 128 + c4);
        wr1[kk] = *(const float4*)(W + (size_t)(k + 1) * 128 + c4);
    }
    {
        const int row = t >> 4, c0 = (t & 15) * 8;
        const float* xr = x + ((size_t)(b * NN + n0 + row)) * FF + c0;
        const float4 v0 = *(const float4*)xr;
        const float4 v1 = *(const float4*)(xr + 4);
        unsigned* dst = (unsigned*)(xt + row * XT_P + c0);
        dst[0] = pk_bf16(v0.x, v0.y); dst[1] = pk_bf16(v0.z, v0.w);
        dst[2] = pk_bf16(v1.x, v1.y); dst[3] = pk_bf16(v1.z, v1.w);
    }
    #pragma unroll
    for (int kk = 0; kk < 8; ++kk) {
        const int k = kh + 2 * kk;
        *(unsigned*)(Wt + (c4 + 0) * WT_P + k) = pk_bf16(wr0[kk].x, wr1[kk].x);
        *(unsigned*)(Wt + (c4 + 1) * WT_P + k) = pk_bf16(wr0[kk].y, wr1[kk].y);
        *(unsigned*)(Wt + (c4 + 2) * WT_P + k) = pk_bf16(wr0[kk].z, wr1[kk].z);
        *(unsigned*)(Wt + (c4 + 3) * WT_P + k) = pk_bf16(wr0[kk].w, wr1[kk].w);
    }
    const int g0 = (2 * w) * 16 + m16, g1 = (2 * w + 1) * 16 + m16;
    const float aw0 = a_w[g0], aw1 = a_w[g1];
    __syncthreads();

    f32x4 acc0 = {}, acc1 = {};
    bf16x8 af[4];
    #pragma unroll
    for (int dk = 0; dk < 4; ++dk)
        af[dk] = *(const bf16x8*)(xt + m16 * XT_P + dk * 32 + q * 8);
    #pragma unroll
    for (int dk = 0; dk < 4; ++dk) {
        bf16x8 b0 = *(const bf16x8*)(Wt + g0 * WT_P + dk * 32 + q * 8);
        bf16x8 b1 = *(const bf16x8*)(Wt + g1 * WT_P + dk * 32 + q * 8);
        acc0 = __builtin_amdgcn_mfma_f32_16x16x32_bf16(af[dk], b0, acc0, 0, 0, 0);
        acc1 = __builtin_amdgcn_mfma_f32_16x16x32_bf16(af[dk], b1, acc1, 0, 0, 0);
    }

    float sp[4];
    #pragma unroll
    for (int r = 0; r < 4; ++r) sp[r] = acc0[r] * aw0 + acc1[r] * aw1;
    #pragma unroll
    for (int off = 1; off < 16; off <<= 1)
        #pragma unroll
        for (int r = 0; r < 4; ++r) sp[r] += __shfl_xor(sp[r], off, 64);
    if (m16 == 0) {
        #pragma unroll
        for (int r = 0; r < 4; ++r) sredw[w * 16 + q * 4 + r] = sp[r];
    }
    {
        uint2 o0 = { pk_bf16(acc0[0], acc0[1]), pk_bf16(acc0[2], acc0[3]) };
        uint2 o1 = { pk_bf16(acc1[0], acc1[1]), pk_bf16(acc1[2], acc1[3]) };
        *(uint2*)(Ht + ((size_t)(b * 128 + g0)) * NN + n0 + q * 4) = o0;
        *(uint2*)(Ht + ((size_t)(b * 128 + g1)) * NN + n0 + q * 4) = o1;
    }
    __syncthreads();
    if (t < 16)
        s_out[b * NN + n0 + t] = sredw[t] + sredw[16 + t] + sredw[32 + t] + sredw[48 + t] + a_b[0];
}

// ---------------- Kernel 2: split-K attention, g-split (no cross-wave O reduce) -----
// Same verified geometry (512 blocks: js(8) x is(16) x b(4), 256-j window, IRND=8,
// h-frags loaded once). NEW dataflow per round:
//   phase P: all waves compute P (exp code byte-identical to verified kernel
//            through fa0/fa1) and write it to LDS (2 x ds_write_b128/lane);
//            rs reduced as before into parity rsw.  ONE barrier.
//   phase M: each wave reads the full P tile back (8 x ds_read_b128) and
//            computes its PRIVATE 32-g output slice (16 MFMAs, acc = 8 regs).
//   epilogue: wave-private LDS transpose scratch -> pk_bf16 -> coalesced b128
//            po store; prs from parity rsw. No O ever crosses waves; per-round
//            cross-wave LDS volume drops 4x; barriers 2 -> 1.
// A streamed with the round-0-verified 1-round register prefetch. b = bx&3 pins
// batches to XCDs (Ht slice L2-resident).
#define JS 8
#define IRND 8
#define P_RW 132   // u32 stride of P rows: optimal 8-lane/bank-quad b128 pattern
#define O_RW 36    // f32 stride of O scratch rows: 16B-aligned rows, ~2-way max

__global__ __launch_bounds__(256, 2) void k2_attn(
    const float* __restrict__ A, const uint16_t* __restrict__ Ht,
    const float* __restrict__ s, uint16_t* __restrict__ po,
    float* __restrict__ prs)
{
    __shared__ unsigned Pbuf[2][16 * P_RW];   // 16.5 KB parity-buffered P
    __shared__ float    Osc[4][16 * O_RW];    // 9 KB wave-private transpose scratch
    __shared__ float    rsw[2][4][16];

    const int t = threadIdx.x;
    const int w = t >> 6, l = t & 63;
    const int m16 = l & 15, q = l >> 4;

    const int bx = blockIdx.x;
    const int b  = bx & 3;                 // XCD-pinned batch
    const int js = (bx >> 2) & 7;
    const int is = bx >> 5;
    const int j0 = js * 256;
    const int ibase = is * 128;

    const float* sb = s + b * NN;
    const float* Ab = A + (size_t)b * NN * NN;
    const uint16_t* Hb = Ht + (size_t)b * FF * NN;

    const int jc0 = j0 + w * 32 + q * 8;
    const int jc1 = j0 + (w + 4) * 32 + q * 8;

    // loop-invariant sj (16 values per lane) — verified pattern
    float4 sj00 = *(const float4*)(sb + jc0);
    float4 sj01 = *(const float4*)(sb + jc0 + 4);
    float4 sj10 = *(const float4*)(sb + jc1);
    float4 sj11 = *(const float4*)(sb + jc1 + 4);

    // h-fragments for THIS WAVE'S g-slice [w*32, w*32+32): B-operand frags for
    // all 8 K-slices of the 256-j window. 16 x b128 = 64 VGPR, held all rounds.
    bf16x8 hf0[8], hf1[8];
    #pragma unroll
    for (int ks = 0; ks < 8; ++ks) {
        const int jj = j0 + ks * 32 + q * 8;
        hf0[ks] = *(const bf16x8*)(Hb + (size_t)(w * 32 + m16) * NN + jj);
        hf1[ks] = *(const bf16x8*)(Hb + (size_t)(w * 32 + 16 + m16) * NN + jj);
    }

    // round-0 A prefetch (lane: row ibase+m16, its 16 j's) — verified pattern
    const float* Ar = Ab + (size_t)(ibase + m16) * NN;
    float4 a00 = *(const float4*)(Ar + jc0);
    float4 a01 = *(const float4*)(Ar + jc0 + 4);
    float4 a10 = *(const float4*)(Ar + jc1);
    float4 a11 = *(const float4*)(Ar + jc1 + 4);
    float si = sb[ibase + m16];

    const size_t slice = (size_t)(js * BB + b);

    #pragma unroll
    for (int r = 0; r < IRND; ++r) {
        const int i0r = ibase + r * 16;
        const int i0n = ibase + ((r + 1) & (IRND - 1)) * 16;
        const int par = r & 1;

        // prefetch next round's A + si (full-round latency cover; wraps harmlessly)
        const float* An = Ab + (size_t)(i0n + m16) * NN;
        float4 n00 = *(const float4*)(An + jc0);
        float4 n01 = *(const float4*)(An + jc0 + 4);
        float4 n10 = *(const float4*)(An + jc1);
        float4 n11 = *(const float4*)(An + jc1 + 4);
        const float sin_ = sb[i0n + m16];

        // ---- phase P: exp + pack (byte-identical math to verified kernel) ----
        const float svv[16] = {sj00.x,sj00.y,sj00.z,sj00.w, sj01.x,sj01.y,sj01.z,sj01.w,
                               sj10.x,sj10.y,sj10.z,sj10.w, sj11.x,sj11.y,sj11.z,sj11.w};
        const float avv[16] = {a00.x,a00.y,a00.z,a00.w, a01.x,a01.y,a01.z,a01.w,
                               a10.x,a10.y,a10.z,a10.w, a11.x,a11.y,a11.z,a11.w};
        float pv[16]; float rs = 0.f;
        #pragma unroll
        for (int j = 0; j < 16; ++j) {
            float e = si + svv[j];
            e = fmaxf(e, 0.2f * e);               // LeakyReLU(0.2)
            pv[j] = __expf(e + avv[j]);
            rs += pv[j];
        }
        union { unsigned u[4]; uint4 v4; } fa0, fa1;
        #pragma unroll
        for (int j = 0; j < 4; ++j) {
            fa0.u[j] = pk_bf16(pv[2 * j], pv[2 * j + 1]);
            fa1.u[j] = pk_bf16(pv[8 + 2 * j], pv[9 + 2 * j]);
        }
        // write P[row=m16][j-chunks w*4+q and w*4+q+16] (u32 cols = j/2)
        *(uint4*)&Pbuf[par][m16 * P_RW + (w * 4 + q) * 4]        = fa0.v4;
        *(uint4*)&Pbuf[par][m16 * P_RW + (w * 4 + q + 16) * 4]   = fa1.v4;

        // row-sum partials: reduce over q within wave (rows = m16)
        rs += __shfl_xor(rs, 16, 64);
        rs += __shfl_xor(rs, 32, 64);
        if (q == 0) rsw[par][w][m16] = rs;

        asm volatile("s_waitcnt lgkmcnt(0)\n\ts_barrier" ::: "memory");  // 1/round

        // ---- phase M: read P, 16 MFMAs into private 32-g slice ----
        bf16x8 pa[8];
        #pragma unroll
        for (int ks = 0; ks < 8; ++ks)
            pa[ks] = *(const bf16x8*)&Pbuf[par][m16 * P_RW + ks * 16 + q * 4];

        f32x4 acc0 = {0.f, 0.f, 0.f, 0.f}, acc1 = {0.f, 0.f, 0.f, 0.f};
        #pragma unroll
        for (int ks = 0; ks < 8; ++ks) {
            acc0 = __builtin_amdgcn_mfma_f32_16x16x32_bf16(pa[ks], hf0[ks], acc0, 0, 0, 0);
            acc1 = __builtin_amdgcn_mfma_f32_16x16x32_bf16(pa[ks], hf1[ks], acc1, 0, 0, 0);
        }

        // ---- epilogue: wave-private transpose scratch -> coalesced po store ----
        // D layout: row i = q*4+reg, col g = (w*32|w*32+16) + m16
        #pragma unroll
        for (int rr = 0; rr < 4; ++rr) {
            Osc[w][(q * 4 + rr) * O_RW + m16]      = acc0[rr];
            Osc[w][(q * 4 + rr) * O_RW + 16 + m16] = acc1[rr];
        }
        {
            const int row = l >> 2, c0 = (l & 3) * 8;
            const float4 u0 = *(const float4*)&Osc[w][row * O_RW + c0];
            const float4 u1 = *(const float4*)&Osc[w][row * O_RW + c0 + 4];
            uint4 ov = { pk_bf16(u0.x, u0.y), pk_bf16(u0.z, u0.w),
                         pk_bf16(u1.x, u1.y), pk_bf16(u1.z, u1.w) };
            *(uint4*)(po + ((slice * NN + i0r + row) * FF + w * 32 + c0)) = ov;
            if (t < 16)
                prs[slice * NN + i0r + t] = rsw[par][0][t] + rsw[par][1][t]
                                          + rsw[par][2][t] + rsw[par][3][t];
        }

        // rotate the 1-round prefetch
        a00 = n00; a01 = n01; a10 = n10; a11 = n11; si = sin_;
    }
}

// ---------------- Kernel 3: reduce 8 partials, normalize, bias (vectorized) ---------
// (verified) Thread handles 8 consecutive g: uint4 po loads, float4 stores.
__global__ __launch_bounds__(256) void k3_red(
    const uint16_t* __restrict__ po, const float* __restrict__ prs,
    const float* __restrict__ bias, float* __restrict__ out)
{
    const int gid = blockIdx.x * 256 + threadIdx.x;
    const int g8 = (gid & 15) * 8;
    const int i = (gid >> 4) & (NN - 1);
    const int b = gid >> 15;                       // NN*16 threads per batch

    float v[8] = {0.f,0.f,0.f,0.f,0.f,0.f,0.f,0.f};
    float rsum = 0.f;
    #pragma unroll
    for (int js = 0; js < JS; ++js) {
        const size_t base = (size_t)(js * BB + b) * NN + i;
        const uint4 pv_ = *(const uint4*)(po + base * FF + g8);
        const unsigned uu[4] = {pv_.x, pv_.y, pv_.z, pv_.w};
        #pragma unroll
        for (int k = 0; k < 4; ++k) {
            union { unsigned u; float f; } lo, hi;
            lo.u = uu[k] << 16;
            hi.u = uu[k] & 0xffff0000u;
            v[2 * k]     += lo.f;
            v[2 * k + 1] += hi.f;
        }
        rsum += prs[base];
    }
    const float inv = 1.0f / rsum;
    const float4 b0 = *(const float4*)(bias + g8);
    const float4 b1 = *(const float4*)(bias + g8 + 4);
    float4 o0 = { v[0]*inv + b0.x, v[1]*inv + b0.y, v[2]*inv + b0.z, v[3]*inv + b0.w };
    float4 o1 = { v[4]*inv + b1.x, v[5]*inv + b1.y, v[6]*inv + b1.z, v[7]*inv + b1.w };
    float* op = out + ((size_t)(b * NN + i)) * FF + g8;
    *(float4*)op = o0;
    *(float4*)(op + 4) = o1;
}

extern "C" void kernel_launch(void* const* d_in, const int* in_sizes, int n_in,
                              void* d_out, int out_size, void* d_ws, size_t ws_size,
                              hipStream_t stream) {
    const float* x    = (const float*)d_in[0];
    const float* A    = (const float*)d_in[1];
    const float* W    = (const float*)d_in[2];
    const float* a_w  = (const float*)d_in[3];
    const float* a_b  = (const float*)d_in[4];
    const float* bias = (const float*)d_in[5];
    float* out = (float*)d_out;

    char* ws = (char*)d_ws;
    uint16_t* Ht = (uint16_t*)ws;                                  // 2 MB
    float* s = (float*)(ws + 2 * 1024 * 1024);                     // 32 KB (pad to 64K)
    uint16_t* po = (uint16_t*)(ws + 2 * 1024 * 1024 + 65536);      // 16 MB
    float* prs = (float*)(ws + 2 * 1024 * 1024 + 65536 + (size_t)JS * BB * NN * FF * 2);  // 256 KB

    k1_proj<<<BB * (NN / 16), 256, 0, stream>>>(x, W, a_w, a_b, Ht, s);
    k2_attn<<<JS * 16 * BB, 256, 0, stream>>>(A, Ht, s, po, prs);
    k3_red<<<(BB * NN * FF) / (256 * 8), 256, 0, stream>>>(po, prs, bias, out);
}